// Round 4
// baseline (196.230 us; speedup 1.0000x reference)
//
#include <hip/hip_runtime.h>

#define NIMG 4
#define NCLS 19
#define CCH  32
#define LH   128
#define LW   128
#define HH   512
#define WW   512
#define HWQ  (LH*LW)    // 16384
#define HWP  (HH*WW)    // 262144

#define TR 8
#define TC 16
#define NTILE 128        // field-role blocks per image
#define HALO_R 36
#define HALO_C 68
#define NHALO (HALO_R*HALO_C)   // 2448
#define QROWS 128        // quad-role blocks per image
#define NBLK (NTILE+QROWS)      // 256 blocks per image
#define ASTR 132         // padded stride (16B-aligned rows)

// field LDS: ET[cell*33+c] 4224 | A[k*132+cell] 2508 | red[w*608+..] 2432
#define L_ET  0
#define L_A   4224
#define L_RED 6732
#define LDS_FLOATS 9164
// quad LDS: S[rowid*132+x] 6336 | QACC[w*20+k] 80
#define L_QS   0
#define L_QACC 6336
// finalize reuse
#define F_CSUM 0
#define F_M    640
#define F_CNT  1280
#define F_S2   1312
#define F_SC   1344     // [0]=intra [1]=nfg [2]=inter

// Bilinear taps, jax.image.resize half-pixel convention (128 -> 512).
// edge renormalization == clamping (verified absmax 0.0 in R1-R3)
__device__ __forceinline__ void taps(int v, int lim, int& i0, int& i1, float& f) {
    int r = v & 3;
    int b = (v >> 2) + ((r < 2) ? -1 : 0);
    f = 0.125f + 0.25f * (float)((r + 2) & 3);
    i0 = b < 0 ? 0 : b;
    i1 = (b + 1 > lim) ? lim : (b + 1);
}

__global__ __launch_bounds__(256, 4) void k_main(const float* __restrict__ E,
        const int* __restrict__ lab, float* __restrict__ P_sum,
        float* __restrict__ P_cnt, float* __restrict__ P_S2,
        int* __restrict__ done, float* __restrict__ out) {
    __shared__ float lds[LDS_FLOATS];
    __shared__ int sLast;
    const int n = blockIdx.y;
    const int tid = threadIdx.x;
    const int bid = blockIdx.x;

    if (bid < NTILE) {
        // ================= field role: A-field + contract =================
        const int ty = bid >> 3, tx = bid & 7;
        const int Y0 = ty * TR, X0 = tx * TC;
        for (int i = tid; i < NCLS * ASTR; i += 256) lds[L_A + i] = 0.f;
        // stage E tile (float4 global, scalar LDS scatter into [cell][c])
#pragma unroll
        for (int it = 0; it < 4; it++) {
            int seg = it * 256 + tid;            // [0,1024)
            int c = seg >> 5, q = seg & 31;
            int cy = q >> 2, cx = (q & 3) * 4;
            const float4 ev = *(const float4*)(E + ((size_t)n * CCH + c) * HWQ
                                               + (Y0 + cy) * LW + X0 + cx);
            int cell = cy * TC + cx;
            lds[L_ET + (cell + 0) * 33 + c] = ev.x;
            lds[L_ET + (cell + 1) * 33 + c] = ev.y;
            lds[L_ET + (cell + 2) * 33 + c] = ev.z;
            lds[L_ET + (cell + 3) * 33 + c] = ev.w;
        }
        // prefetch halo labels (independent loads, single drain)
        const int* ln = lab + (size_t)n * HWP;
        const int h_lo = Y0 * 4 - 2, w_lo = X0 * 4 - 2;
        int Lv[10];
#pragma unroll
        for (int it = 0; it < 10; it++) {
            int i = it * 256 + tid;
            int hr = i / HALO_C, wc = i - hr * HALO_C;
            int h = h_lo + hr, w = w_lo + wc;
            bool ok = (i < NHALO) & (h >= 0) & (h < HH) & (w >= 0) & (w < WW);
            int hc = h < 0 ? 0 : (h > HH - 1 ? HH - 1 : h);
            int wl = w < 0 ? 0 : (w > WW - 1 ? WW - 1 : w);
            int lv = ln[hc * WW + wl];
            Lv[it] = ok ? lv : -1;
        }
        __syncthreads();
#pragma unroll
        for (int it = 0; it < 10; it++) {
            if (Lv[it] < 0) continue;
            int i = it * 256 + tid;
            int hr = i / HALO_C, wc = i - hr * HALO_C;
            int h = h_lo + hr, w = w_lo + wc;
            int y0, y1, x0, x1; float fy, fx;
            taps(h, LH - 1, y0, y1, fy);
            taps(w, LW - 1, x0, x1, fx);
            int yy[2] = {y0, y1}; float wy[2] = {1.f - fy, fy};
            int xx[2] = {x0, x1}; float wx[2] = {1.f - fx, fx};
            float* Ar = &lds[L_A + Lv[it] * ASTR];
#pragma unroll
            for (int a = 0; a < 2; a++) {
#pragma unroll
                for (int b = 0; b < 2; b++) {
                    int ry = yy[a] - Y0, rx = xx[b] - X0;
                    if (ry >= 0 && ry < TR && rx >= 0 && rx < TC)
                        atomicAdd(&Ar[ry * TC + rx], wy[a] * wx[b]);
                }
            }
        }
        __syncthreads();
        // contract: thread (g,c); A via ds_read_b128, E via conflict-free b32
        const int g = tid >> 5, c = tid & 31;
        float acc[NCLS];
#pragma unroll
        for (int k = 0; k < NCLS; k++) acc[k] = 0.f;
#pragma unroll
        for (int j4 = 0; j4 < 4; j4++) {
            int cell0 = g * 16 + j4 * 4;
            float e0 = lds[L_ET + (cell0 + 0) * 33 + c];
            float e1 = lds[L_ET + (cell0 + 1) * 33 + c];
            float e2 = lds[L_ET + (cell0 + 2) * 33 + c];
            float e3 = lds[L_ET + (cell0 + 3) * 33 + c];
#pragma unroll
            for (int k = 0; k < NCLS; k++) {
                const float4 a = *(const float4*)&lds[L_A + k * ASTR + cell0];
                acc[k] = fmaf(a.x, e0, fmaf(a.y, e1, fmaf(a.z, e2, fmaf(a.w, e3, acc[k]))));
            }
        }
#pragma unroll
        for (int k = 0; k < NCLS; k++) acc[k] += __shfl_xor(acc[k], 32);
        const int wv = tid >> 6;
        if ((tid & 63) < 32) {
#pragma unroll
            for (int k = 0; k < NCLS; k++) lds[L_RED + wv * 608 + k * 32 + c] = acc[k];
        }
        __syncthreads();
        float* Ps = P_sum + (size_t)(n * NTILE + bid) * 608;
        for (int i = tid; i < 608; i += 256)
            Ps[i] = lds[L_RED + i] + lds[L_RED + 608 + i]
                  + lds[L_RED + 1216 + i] + lds[L_RED + 1824 + i];
        if (tid < NCLS) {
            float s = 0.f;
#pragma unroll
            for (int q = 0; q < 32; q++) {
                const float4 a = *(const float4*)&lds[L_A + tid * ASTR + q * 4];
                s += a.x + a.y + a.z + a.w;
            }
            P_cnt[((size_t)n * NCLS + tid) * NTILE + bid] = s;
        }
    } else {
        // ================= quad role: S2 partials via LDS stencil ==========
        const int by = bid - NTILE;
        const int grp = tid >> 7, bx = tid & 127;
        if ((tid & 63) < 20) lds[L_QACC + (tid >> 6) * 20 + (tid & 63)] = 0.f;
        const int r0 = (by == 0) ? 0 : by - 1;
        const int r2 = (by == LH - 1) ? LH - 1 : by + 1;
        const int xm = (bx == 0) ? 0 : bx - 1;
        const int xp = (bx == LW - 1) ? LW - 1 : bx + 1;
        float d2[16];
#pragma unroll
        for (int i = 0; i < 16; i++) d2[i] = 0.f;
        const float* En = E + (size_t)n * CCH * HWQ;

#pragma unroll
        for (int half = 0; half < 2; half++) {
            __syncthreads();
            // stage 16 ch x 3 rows x 128 cols, float4 in+out
#pragma unroll
            for (int it = 0; it < 6; it++) {
                int seg = it * 256 + tid;        // [0,1536)
                int rowid = seg >> 5, x4 = (seg & 31) * 4;
                int c = rowid / 3, r = rowid - c * 3;
                int row = (r == 0) ? r0 : ((r == 1) ? by : r2);
                const float4 ev = *(const float4*)(En + (size_t)(half * 16 + c) * HWQ
                                                   + row * LW + x4);
                *(float4*)&lds[L_QS + rowid * ASTR + x4] = ev;
            }
            __syncthreads();
#pragma unroll
            for (int j = 0; j < 8; j++) {
                const float* R0 = &lds[L_QS + ((grp * 8 + j) * 3) * ASTR];
                const float* R1 = R0 + ASTR;
                const float* R2 = R1 + ASTR;
                float e00 = R0[xm], e01 = R0[bx], e02 = R0[xp];
                float e10 = R1[xm], e11 = R1[bx], e12 = R1[xp];
                float e20 = R2[xm], e21 = R2[bx], e22 = R2[xp];
                float dy0 = e10 - e00, dy1 = e11 - e01, dy2 = e12 - e02;
                float dz0 = e20 - e10, dz1 = e21 - e11, dz2 = e22 - e12;
                float ry[4][3];
                ry[0][0] = fmaf(0.625f, dy0, e00); ry[0][1] = fmaf(0.625f, dy1, e01); ry[0][2] = fmaf(0.625f, dy2, e02);
                ry[1][0] = fmaf(0.875f, dy0, e00); ry[1][1] = fmaf(0.875f, dy1, e01); ry[1][2] = fmaf(0.875f, dy2, e02);
                ry[2][0] = fmaf(0.125f, dz0, e10); ry[2][1] = fmaf(0.125f, dz1, e11); ry[2][2] = fmaf(0.125f, dz2, e12);
                ry[3][0] = fmaf(0.375f, dz0, e10); ry[3][1] = fmaf(0.375f, dz1, e11); ry[3][2] = fmaf(0.375f, dz2, e12);
#pragma unroll
                for (int r = 0; r < 4; r++) {
                    float da = ry[r][1] - ry[r][0], db = ry[r][2] - ry[r][1];
                    float v0 = fmaf(0.625f, da, ry[r][0]);
                    float v1 = fmaf(0.875f, da, ry[r][0]);
                    float v2 = fmaf(0.125f, db, ry[r][1]);
                    float v3 = fmaf(0.375f, db, ry[r][1]);
                    d2[r * 4 + 0] = fmaf(v0, v0, d2[r * 4 + 0]);
                    d2[r * 4 + 1] = fmaf(v1, v1, d2[r * 4 + 1]);
                    d2[r * 4 + 2] = fmaf(v2, v2, d2[r * 4 + 2]);
                    d2[r * 4 + 3] = fmaf(v3, v3, d2[r * 4 + 3]);
                }
            }
        }
        // labels (prefetched) + per-wave LDS atomics
        const int* lp = lab + (size_t)n * HWP + (by * 4) * WW + bx * 4;
        int4 lv[4];
#pragma unroll
        for (int r = 0; r < 4; r++) lv[r] = *(const int4*)(lp + r * WW);
        float* accW = &lds[L_QACC + (tid >> 6) * 20];
#pragma unroll
        for (int r = 0; r < 4; r++) {
            atomicAdd(&accW[lv[r].x], d2[r * 4 + 0]);
            atomicAdd(&accW[lv[r].y], d2[r * 4 + 1]);
            atomicAdd(&accW[lv[r].z], d2[r * 4 + 2]);
            atomicAdd(&accW[lv[r].w], d2[r * 4 + 3]);
        }
        __syncthreads();
        if (tid < NCLS) {
            float s = lds[L_QACC + tid] + lds[L_QACC + 20 + tid]
                    + lds[L_QACC + 40 + tid] + lds[L_QACC + 60 + tid];
            P_S2[((size_t)n * NCLS + tid) * QROWS + by] = s;
        }
    }

    // ================= done-counter + last-block finalize =================
    __threadfence();
    __syncthreads();
    if (tid == 0) {
        int old = atomicAdd(&done[n], 1);
        sLast = (old == NBLK - 1) ? 1 : 0;
        if (sLast) __threadfence();
    }
    __syncthreads();
    if (!sLast) return;

    const float* Ps = P_sum + (size_t)n * NTILE * 608;
    for (int base = 0; base < 608; base += 256) {
        int idx = base + tid;
        if (idx < 608) {
            float s = 0.f;
#pragma unroll 4
            for (int b = 0; b < NTILE; b++) s += Ps[(size_t)b * 608 + idx];
            lds[F_CSUM + (idx >> 5) * 33 + (idx & 31)] = s;
        }
    }
    if (tid < 152) {
        int k = tid >> 3, j = tid & 7;
        const float* pc = P_cnt + ((size_t)n * NCLS + k) * NTILE;
        const float* ps = P_S2 + ((size_t)n * NCLS + k) * QROWS;
        float sc = 0.f, s2 = 0.f;
        for (int i = j; i < NTILE; i += 8) { sc += pc[i]; s2 += ps[i]; }
        sc += __shfl_xor(sc, 4); sc += __shfl_xor(sc, 2); sc += __shfl_xor(sc, 1);
        s2 += __shfl_xor(s2, 4); s2 += __shfl_xor(s2, 2); s2 += __shfl_xor(s2, 1);
        if (j == 0) { lds[F_CNT + k] = sc; lds[F_S2 + k] = s2; }
    }
    if (tid == 0) lds[F_SC + 2] = 0.f;
    __syncthreads();
    for (int base = 0; base < 608; base += 256) {
        int idx = base + tid;
        if (idx < 608) {
            int k = idx >> 5, c = idx & 31;
            lds[F_M + k * 33 + c] = lds[F_CSUM + k * 33 + c] / (lds[F_CNT + k] + 1.f);
        }
    }
    __syncthreads();
    // intra + n_fg (threads 1..18 in wave 0)
    float vi = 0.f, fg = 0.f;
    if (tid >= 1 && tid < NCLS && lds[F_CNT + tid] > 0.f) {
        fg = 1.f;
        float ct = lds[F_CNT + tid];
        float dot = 0.f, mm = 0.f;
#pragma unroll
        for (int c = 0; c < CCH; c++) {
            float mv = lds[F_M + tid * 33 + c];
            dot = fmaf(mv, lds[F_CSUM + tid * 33 + c], dot);
            mm = fmaf(mv, mv, mm);
        }
        vi = (lds[F_S2 + tid] - 2.f * dot + ct * mm) * (1.f / 32.f) / (ct + 1.f);
    }
#pragma unroll
    for (int s_ = 32; s_ >= 1; s_ >>= 1) { vi += __shfl_xor(vi, s_); fg += __shfl_xor(fg, s_); }
    if (tid == 0) { lds[F_SC] = vi; lds[F_SC + 1] = fg; }
    // inter: 18x18 pairs
    float ve = 0.f;
    for (int p = tid; p < 324; p += 256) {
        int j = 1 + p / 18, k = 1 + p % 18;
        if (lds[F_CNT + j] > 0.f && lds[F_CNT + k] > 0.f) {
            float s = 0.f;
#pragma unroll
            for (int c = 0; c < CCH; c++) {
                float d = lds[F_M + j * 33 + c] - lds[F_M + k * 33 + c];
                s = fmaf(d, d, s);
            }
            ve += s * (1.f / 32.f);
        }
    }
#pragma unroll
    for (int s_ = 32; s_ >= 1; s_ >>= 1) ve += __shfl_xor(ve, s_);
    if ((tid & 63) == 0) atomicAdd(&lds[F_SC + 2], ve);
    __syncthreads();
    if (tid == 0) {
        float nfg = lds[F_SC + 1];
        out[n] = lds[F_SC] / nfg - lds[F_SC + 2] / (nfg * nfg);
    }
}

extern "C" void kernel_launch(void* const* d_in, const int* in_sizes, int n_in,
                              void* d_out, int out_size, void* d_ws, size_t ws_size,
                              hipStream_t stream) {
    const float* E = (const float*)d_in[0];   // (4,32,128,128) fp32
    const int* lab = (const int*)d_in[1];     // (4,512,512) int
    float* out = (float*)d_out;               // (4,) fp32

    int* done = (int*)d_ws;                                   // 4 counters (16 B)
    float* P_sum = (float*)d_ws + 16;                         // 4*128*608
    float* P_cnt = P_sum + (size_t)NIMG * NTILE * NCLS * CCH; // 4*19*128
    float* P_S2  = P_cnt + (size_t)NIMG * NCLS * NTILE;       // 4*19*128

    hipMemsetAsync(d_ws, 0, 16, stream);   // zero done counters only
    k_main<<<dim3(NBLK, NIMG), dim3(256), 0, stream>>>(E, lab, P_sum, P_cnt, P_S2, done, out);
}

// Round 5
// 126.725 us; speedup vs baseline: 1.5485x; 1.5485x over previous
//
#include <hip/hip_runtime.h>

#define NIMG 4
#define NCLS 19
#define CCH  32
#define LH   128
#define LW   128
#define HH   512
#define WW   512
#define HWQ  (LH*LW)    // 16384
#define HWP  (HH*WW)    // 262144

#define TR 8
#define TC 16
#define NTILE 128        // field-role blocks per image (16x8 tiles)
#define TCELLS 128
#define HALO_R 36
#define HALO_C 68
#define NHALO (HALO_R*HALO_C)   // 2448
#define QB2 256          // quad-role blocks per image (row x channel-half)

// field LDS: ET[cell*33+c] 4224 | A[cell*19+L] 2432 | red[w*608+..] 2432
#define L_ET  0
#define L_A   4224
#define L_RED 6656
#define LDS_FLOATS 9088  // 36.3 KB -> 4 blocks/CU

// Bilinear taps, jax.image.resize half-pixel convention (128 -> 512).
// edge renormalization == clamping (verified absmax 0.0 in R1-R4)
__device__ __forceinline__ void taps(int v, int lim, int& i0, int& i1, float& f) {
    int r = v & 3;
    int b = (v >> 2) + ((r < 2) ? -1 : 0);
    f = 0.125f + 0.25f * (float)((r + 2) & 3);
    i0 = b < 0 ? 0 : b;
    i1 = (b + 1 > lim) ? lim : (b + 1);
}

__global__ __launch_bounds__(256) void k_main(const float* __restrict__ E,
        const int* __restrict__ lab, float* __restrict__ P_sum,
        float* __restrict__ P_cnt, float* __restrict__ P_S2) {
    __shared__ float lds[LDS_FLOATS];
    const int n = blockIdx.y;
    const int tid = threadIdx.x;
    const int bid = blockIdx.x;

    if (bid < NTILE) {
        // ================= field role: A-field + fused contract =============
        const int ty = bid >> 3, tx = bid & 7;
        const int Y0 = ty * TR, X0 = tx * TC;
        for (int i = tid; i < TCELLS * NCLS; i += 256) lds[L_A + i] = 0.f;
        // stage E tile scalar (coalesced global, conflict-free LDS)
#pragma unroll
        for (int it = 0; it < 16; it++) {
            int idx = it * 256 + tid;             // [0,4096)
            int c = idx >> 7, cell = idx & 127;
            int cy = cell >> 4, cx = cell & 15;
            float e = E[((size_t)n * CCH + c) * HWQ + (Y0 + cy) * LW + (X0 + cx)];
            lds[L_ET + cell * 33 + c] = e;
        }
        // prefetch halo labels into registers (independent loads, one drain)
        const int* ln = lab + (size_t)n * HWP;
        const int h_lo = Y0 * 4 - 2, w_lo = X0 * 4 - 2;
        int Lv[10];
#pragma unroll
        for (int it = 0; it < 10; it++) {
            int i = it * 256 + tid;
            int hr = i / HALO_C, wc = i - hr * HALO_C;
            int h = h_lo + hr, w = w_lo + wc;
            bool ok = (i < NHALO) & (h >= 0) & (h < HH) & (w >= 0) & (w < WW);
            int hc = h < 0 ? 0 : (h > HH - 1 ? HH - 1 : h);
            int wl = w < 0 ? 0 : (w > WW - 1 ? WW - 1 : w);
            int lv = ln[hc * WW + wl];
            Lv[it] = ok ? lv : -1;
        }
        __syncthreads();
#pragma unroll
        for (int it = 0; it < 10; it++) {
            if (Lv[it] < 0) continue;
            int i = it * 256 + tid;
            int hr = i / HALO_C, wc = i - hr * HALO_C;
            int h = h_lo + hr, w = w_lo + wc;
            int y0, y1, x0, x1; float fy, fx;
            taps(h, LH - 1, y0, y1, fy);
            taps(w, LW - 1, x0, x1, fx);
            int yy[2] = {y0, y1}; float wy[2] = {1.f - fy, fy};
            int xx[2] = {x0, x1}; float wx[2] = {1.f - fx, fx};
#pragma unroll
            for (int a = 0; a < 2; a++) {
#pragma unroll
                for (int b = 0; b < 2; b++) {
                    int ry = yy[a] - Y0, rx = xx[b] - X0;
                    if (ry >= 0 && ry < TR && rx >= 0 && rx < TC)
                        atomicAdd(&lds[L_A + (ry * TC + rx) * NCLS + Lv[it]], wy[a] * wx[b]);
                }
            }
        }
        __syncthreads();
        // contract: thread (g,c); E lane-consecutive LDS, A broadcast
        const int g = tid >> 5, c = tid & 31;
        float acc[NCLS];
#pragma unroll
        for (int k = 0; k < NCLS; k++) acc[k] = 0.f;
#pragma unroll
        for (int j = 0; j < 16; j++) {
            int cell = g * 16 + j;
            float e = lds[L_ET + cell * 33 + c];
            const float* Ar = &lds[L_A + cell * NCLS];
#pragma unroll
            for (int k = 0; k < NCLS; k++) acc[k] = fmaf(Ar[k], e, acc[k]);
        }
#pragma unroll
        for (int k = 0; k < NCLS; k++) acc[k] += __shfl_xor(acc[k], 32);
        const int wv = tid >> 6;
        if ((tid & 63) < 32) {
#pragma unroll
            for (int k = 0; k < NCLS; k++) lds[L_RED + wv * 608 + k * 32 + c] = acc[k];
        }
        __syncthreads();
        float* Ps = P_sum + (size_t)(n * NTILE + bid) * 608;
        for (int i = tid; i < 608; i += 256)
            Ps[i] = lds[L_RED + i] + lds[L_RED + 608 + i]
                  + lds[L_RED + 1216 + i] + lds[L_RED + 1824 + i];
        if (tid < NCLS) {
            float s = 0.f;
            for (int cell = 0; cell < TCELLS; cell++) s += lds[L_A + cell * NCLS + tid];
            P_cnt[((size_t)n * NCLS + tid) * NTILE + bid] = s;
        }
    } else {
        // ================ quad role: S2 partial, one row x 16 channels ======
        const int qb = bid - NTILE;              // 0..255
        const int by = qb >> 1;                  // low-res row
        const int ch0 = (qb & 1) * 16 + (tid >> 7) * 8;  // 8 channels/thread
        const int bx = tid & 127;
        if (tid < NCLS) lds[tid] = 0.f;
        __syncthreads();

        const float* En = E + (size_t)n * CCH * HWQ;
        const int r0 = (by == 0) ? 0 : by - 1;
        const int r2 = (by == LH - 1) ? LH - 1 : by + 1;
        const int c0 = (bx == 0) ? 0 : bx - 1;
        const int c2 = (bx == LW - 1) ? LW - 1 : bx + 1;
        const int o0 = r0 * LW, o1 = by * LW, o2 = r2 * LW;

        float d2[16];
#pragma unroll
        for (int i = 0; i < 16; i++) d2[i] = 0.f;

#pragma unroll 2
        for (int c = 0; c < 8; c++) {
            const float* Ep = En + (size_t)(ch0 + c) * HWQ;
            float e00 = Ep[o0 + c0], e01 = Ep[o0 + bx], e02 = Ep[o0 + c2];
            float e10 = Ep[o1 + c0], e11 = Ep[o1 + bx], e12 = Ep[o1 + c2];
            float e20 = Ep[o2 + c0], e21 = Ep[o2 + bx], e22 = Ep[o2 + c2];
            float dy0 = e10 - e00, dy1 = e11 - e01, dy2 = e12 - e02;
            float dz0 = e20 - e10, dz1 = e21 - e11, dz2 = e22 - e12;
            float ry[4][3];
            ry[0][0] = fmaf(0.625f, dy0, e00); ry[0][1] = fmaf(0.625f, dy1, e01); ry[0][2] = fmaf(0.625f, dy2, e02);
            ry[1][0] = fmaf(0.875f, dy0, e00); ry[1][1] = fmaf(0.875f, dy1, e01); ry[1][2] = fmaf(0.875f, dy2, e02);
            ry[2][0] = fmaf(0.125f, dz0, e10); ry[2][1] = fmaf(0.125f, dz1, e11); ry[2][2] = fmaf(0.125f, dz2, e12);
            ry[3][0] = fmaf(0.375f, dz0, e10); ry[3][1] = fmaf(0.375f, dz1, e11); ry[3][2] = fmaf(0.375f, dz2, e12);
#pragma unroll
            for (int r = 0; r < 4; r++) {
                float da = ry[r][1] - ry[r][0], db = ry[r][2] - ry[r][1];
                float v0 = fmaf(0.625f, da, ry[r][0]);
                float v1 = fmaf(0.875f, da, ry[r][0]);
                float v2 = fmaf(0.125f, db, ry[r][1]);
                float v3 = fmaf(0.375f, db, ry[r][1]);
                d2[r * 4 + 0] = fmaf(v0, v0, d2[r * 4 + 0]);
                d2[r * 4 + 1] = fmaf(v1, v1, d2[r * 4 + 1]);
                d2[r * 4 + 2] = fmaf(v2, v2, d2[r * 4 + 2]);
                d2[r * 4 + 3] = fmaf(v3, v3, d2[r * 4 + 3]);
            }
        }
        const int* lp = lab + (size_t)n * HWP + (by * 4) * WW + bx * 4;
#pragma unroll
        for (int r = 0; r < 4; r++) {
            int4 l4 = *(const int4*)(lp + r * WW);
            atomicAdd(&lds[l4.x], d2[r * 4 + 0]);
            atomicAdd(&lds[l4.y], d2[r * 4 + 1]);
            atomicAdd(&lds[l4.z], d2[r * 4 + 2]);
            atomicAdd(&lds[l4.w], d2[r * 4 + 3]);
        }
        __syncthreads();
        if (tid < NCLS)
            P_S2[((size_t)n * NCLS + tid) * QB2 + qb] = lds[tid];
    }
}

// reduce partials; intra = (S2 - 2 m.s + cnt|m|^2)/32/(cnt+1); inter pairwise
__global__ __launch_bounds__(640) void k_final(const float* __restrict__ P_sum,
        const float* __restrict__ P_cnt, const float* __restrict__ P_S2,
        float* __restrict__ out) {
    const int n = blockIdx.x, t = threadIdx.x;
    __shared__ float csum[NCLS * 33];
    __shared__ float m[NCLS * 33];
    __shared__ float cnt[NCLS];
    __shared__ float S2[NCLS];
    __shared__ float sIntra, sNfg, sInter;
    if (t == 0) sInter = 0.f;

    if (t < NCLS * CCH) {
        const int k = t >> 5, c = t & 31;
        const float* p = P_sum + (size_t)n * NTILE * (NCLS * CCH) + t;
        float s = 0.f;
        for (int b = 0; b < NTILE; b++) s += p[b * (NCLS * CCH)];
        csum[k * 33 + c] = s;
        const float* pc = P_cnt + ((size_t)n * NCLS + k) * NTILE;
        float sc = 0.f;
        for (int i = c; i < NTILE; i += 32) sc += pc[i];
        const float* ps = P_S2 + ((size_t)n * NCLS + k) * QB2;
        float s2 = 0.f;
        for (int i = c; i < QB2; i += 32) s2 += ps[i];
#pragma unroll
        for (int mk = 16; mk >= 1; mk >>= 1) {
            sc += __shfl_xor(sc, mk);
            s2 += __shfl_xor(s2, mk);
        }
        if (c == 0) { cnt[k] = sc; S2[k] = s2; }
    }
    __syncthreads();
    if (t < NCLS * CCH) {
        const int k = t >> 5, c = t & 31;
        m[k * 33 + c] = csum[k * 33 + c] / (cnt[k] + 1.f);
    }
    __syncthreads();

    // intra + n_fg (threads 1..18 live in wave 0)
    float vi = 0.f, fg = 0.f;
    if (t >= 1 && t < NCLS && cnt[t] > 0.f) {
        fg = 1.f;
        float dot = 0.f, mm = 0.f;
#pragma unroll
        for (int c = 0; c < CCH; c++) {
            float mv = m[t * 33 + c];
            dot = fmaf(mv, csum[t * 33 + c], dot);
            mm = fmaf(mv, mv, mm);
        }
        vi = (S2[t] - 2.f * dot + cnt[t] * mm) * (1.f / 32.f) / (cnt[t] + 1.f);
    }
#pragma unroll
    for (int s_ = 32; s_ >= 1; s_ >>= 1) { vi += __shfl_xor(vi, s_); fg += __shfl_xor(fg, s_); }
    if (t == 0) { sIntra = vi; sNfg = fg; }

    // inter: 18x18 foreground pairs
    float ve = 0.f;
    if (t < 324) {
        int j = 1 + t / 18, k = 1 + t % 18;
        if (cnt[j] > 0.f && cnt[k] > 0.f) {
            float s = 0.f;
#pragma unroll
            for (int c = 0; c < CCH; c++) {
                float d = m[j * 33 + c] - m[k * 33 + c];
                s = fmaf(d, d, s);
            }
            ve = s * (1.f / 32.f);
        }
    }
#pragma unroll
    for (int s_ = 32; s_ >= 1; s_ >>= 1) ve += __shfl_xor(ve, s_);
    if ((t & 63) == 0) atomicAdd(&sInter, ve);
    __syncthreads();
    if (t == 0) out[n] = sIntra / sNfg - sInter / (sNfg * sNfg);
}

extern "C" void kernel_launch(void* const* d_in, const int* in_sizes, int n_in,
                              void* d_out, int out_size, void* d_ws, size_t ws_size,
                              hipStream_t stream) {
    const float* E = (const float*)d_in[0];   // (4,32,128,128) fp32
    const int* lab = (const int*)d_in[1];     // (4,512,512) int
    float* out = (float*)d_out;               // (4,) fp32

    float* ws = (float*)d_ws;
    float* P_sum = ws;                                          // 4*128*608
    float* P_cnt = P_sum + (size_t)NIMG * NTILE * NCLS * CCH;   // 4*19*128
    float* P_S2  = P_cnt + (size_t)NIMG * NCLS * NTILE;         // 4*19*256
    // every partial slot fully overwritten each call -> no memset

    k_main <<<dim3(NTILE + QB2, NIMG), dim3(256), 0, stream>>>(E, lab, P_sum, P_cnt, P_S2);
    k_final<<<dim3(NIMG), dim3(640), 0, stream>>>(P_sum, P_cnt, P_S2, out);
}